// Round 3
// baseline (237.717 us; speedup 1.0000x reference)
//
#include <hip/hip_runtime.h>

typedef __attribute__((ext_vector_type(8))) short short8;
typedef __attribute__((ext_vector_type(4))) float f32x4;

#define BB 2
#define TT 2048
#define HH 16
#define DD 64
#define CC 1024

__device__ __forceinline__ unsigned short f2bf(float f) {
  union { float f; unsigned int u; } v; v.f = f;
  unsigned int r = v.u + 0x7fffu + ((v.u >> 16) & 1u);
  return (unsigned short)(r >> 16);
}
__device__ __forceinline__ float bf2f(unsigned short h) {
  union { unsigned int u; float f; } v; v.u = ((unsigned int)h) << 16; return v.f;
}

__global__ void cvt_f32_bf16(const float* __restrict__ in, unsigned short* __restrict__ out, int n) {
  int i = blockIdx.x * blockDim.x + threadIdx.x;
  int stride = gridDim.x * blockDim.x;
  for (; i < n; i += stride) out[i] = f2bf(in[i]);
}

// C = A @ B^T ; A [M,K] bf16, B [N,K] bf16, C [M,N] bf16 or f32
template<bool BF16OUT>
__global__ __launch_bounds__(256) void gemm_bt(const unsigned short* __restrict__ A,
                                               const unsigned short* __restrict__ B,
                                               void* __restrict__ Cv,
                                               int M, int N, int K) {
  constexpr int BK = 64, LDT = BK + 8;
  __shared__ unsigned short As[128 * LDT];
  __shared__ unsigned short Bs[128 * LDT];
  const int bm = blockIdx.y * 128, bn = blockIdx.x * 128;
  const int tid = threadIdx.x, wave = tid >> 6, lane = tid & 63;
  const int wm = (wave >> 1) * 64, wn = (wave & 1) * 64;
  const int g = lane >> 4, lr = lane & 15;
  f32x4 acc[4][4];
  #pragma unroll
  for (int i = 0; i < 4; ++i)
    #pragma unroll
    for (int j = 0; j < 4; ++j) acc[i][j] = (f32x4){0.f, 0.f, 0.f, 0.f};

  for (int k0 = 0; k0 < K; k0 += BK) {
    __syncthreads();
    #pragma unroll
    for (int p = 0; p < 4; ++p) {
      int r = p * 32 + (tid >> 3);
      int c = (tid & 7) * 8;
      *(short8*)&As[r * LDT + c] = *(const short8*)&A[(size_t)(bm + r) * K + k0 + c];
      *(short8*)&Bs[r * LDT + c] = *(const short8*)&B[(size_t)(bn + r) * K + k0 + c];
    }
    __syncthreads();
    #pragma unroll
    for (int kk = 0; kk < BK; kk += 32) {
      const int kb = kk + g * 8;
      short8 af[4], bf[4];
      #pragma unroll
      for (int i = 0; i < 4; ++i) {
        af[i] = *(const short8*)&As[(wm + i * 16 + lr) * LDT + kb];
        bf[i] = *(const short8*)&Bs[(wn + i * 16 + lr) * LDT + kb];
      }
      #pragma unroll
      for (int i = 0; i < 4; ++i)
        #pragma unroll
        for (int j = 0; j < 4; ++j)
          acc[i][j] = __builtin_amdgcn_mfma_f32_16x16x32_bf16(af[i], bf[j], acc[i][j], 0, 0, 0);
    }
  }
  #pragma unroll
  for (int i = 0; i < 4; ++i) {
    const int row0 = bm + wm + i * 16 + g * 4;
    #pragma unroll
    for (int j = 0; j < 4; ++j) {
      const int col = bn + wn + j * 16 + lr;
      #pragma unroll
      for (int r = 0; r < 4; ++r) {
        float v = acc[i][j][r];
        if (BF16OUT) ((unsigned short*)Cv)[(size_t)(row0 + r) * N + col] = f2bf(v);
        else         ((float*)Cv)[(size_t)(row0 + r) * N + col] = v;
      }
    }
  }
}

// qkv [B*T, 3*C] bf16 -> rope'd q (pre-scaled by log2e/sqrt(D)) and k, each [B,H,T,D] bf16
__global__ void rope_qk(const unsigned short* __restrict__ qkv,
                        const float* __restrict__ cosb, const float* __restrict__ sinb,
                        unsigned short* __restrict__ qo, unsigned short* __restrict__ ko) {
  int idx = blockIdx.x * blockDim.x + threadIdx.x;
  int d = idx & 31;
  int h = (idx >> 5) & 15;
  int t = (idx >> 9) & 2047;
  int b = idx >> 20;
  const unsigned short* row = qkv + (size_t)(b * TT + t) * (3 * CC);
  float c = cosb[t * DD + d], s = sinb[t * DD + d];
  float q1 = bf2f(row[h * DD + d]),      q2 = bf2f(row[h * DD + d + 32]);
  float k1 = bf2f(row[CC + h * DD + d]), k2 = bf2f(row[CC + h * DD + d + 32]);
  size_t o = (((size_t)(b * HH + h)) * TT + t) * DD + d;
  const float QS = 0.125f * 1.44269504089f;   // 1/sqrt(64) * log2(e): softmax in exp2 domain
  qo[o]      = f2bf(QS * (q1 * c - q2 * s));
  qo[o + 32] = f2bf(QS * (q2 * c + q1 * s));
  ko[o]      = f2bf(k1 * c - k2 * s);
  ko[o + 32] = f2bf(k2 * c + k1 * s);
}

// V slice of qkv -> vt [B,H,D,T] (transposed), LDS tiled, coalesced both sides
__global__ __launch_bounds__(256) void vtrans(const unsigned short* __restrict__ qkv,
                                              unsigned short* __restrict__ vt) {
  __shared__ unsigned short tile[64 * 72];
  const int bh = blockIdx.y, b = bh >> 4, h = bh & 15;
  const int t0 = blockIdx.x * 64;
  const int tid = threadIdx.x;
  const int r = tid >> 2, c0 = (tid & 3) * 16;
  const unsigned short* src = qkv + (size_t)(b * TT + t0 + r) * (3 * CC) + 2 * CC + h * DD + c0;
  *(short8*)&tile[r * 72 + c0]     = *(const short8*)src;
  *(short8*)&tile[r * 72 + c0 + 8] = *(const short8*)(src + 8);
  __syncthreads();
  short8 o0, o1;
  #pragma unroll
  for (int e = 0; e < 8; ++e) {
    ((unsigned short*)&o0)[e] = tile[(c0 + e) * 72 + r];
    ((unsigned short*)&o1)[e] = tile[(c0 + 8 + e) * 72 + r];
  }
  size_t dst = ((size_t)(bh * DD + r)) * TT + t0 + c0;
  *(short8*)&vt[dst]     = o0;
  *(short8*)&vt[dst + 8] = o1;
}

// Flash attention, causal, barrier-free. 1024 blocks x 4 independent waves.
// Each wave: 16 q-rows, K/V fragments straight from global (L2-resident per head).
// Block remap: XCD c gets heads 4c..4c+3 (K+V = 2MB fits 4MB XCD L2), heavy q-tiles first.
__global__ __launch_bounds__(256, 4) void attn3(const unsigned short* __restrict__ qb,
                                                const unsigned short* __restrict__ kb,
                                                const unsigned short* __restrict__ vt,
                                                unsigned short* __restrict__ aout) {
  constexpr int LDT = 72;
  __shared__ unsigned short Pw[4][16 * LDT];
  const int L = blockIdx.x;
  const int xcd = L & 7, m = L >> 3;
  const int bh = xcd * 4 + (m & 3);
  const int qi = 31 - (m >> 2);                 // heavy blocks dispatch first
  const int qbase = qi * 64;
  const int tid = threadIdx.x, wave = tid >> 6, lane = tid & 63;
  const int g = lane >> 4, lr = lane & 15;
  const unsigned short* Qb  = qb + (size_t)bh * TT * DD;
  const unsigned short* Kb  = kb + (size_t)bh * TT * DD;
  const unsigned short* Vtb = vt + (size_t)bh * DD * TT;
  const int rowbase = qbase + wave * 16;

  short8 qf[2];
  #pragma unroll
  for (int kk = 0; kk < 2; ++kk)
    qf[kk] = *(const short8*)&Qb[(size_t)(rowbase + lr) * DD + kk * 32 + g * 8];

  f32x4 acc[4];
  float m_i[4], l_i[4];
  #pragma unroll
  for (int j = 0; j < 4; ++j) acc[j] = (f32x4){0.f, 0.f, 0.f, 0.f};
  #pragma unroll
  for (int r = 0; r < 4; ++r) { m_i[r] = -1e30f; l_i[r] = 0.f; }

  for (int t = 0; t <= qi; ++t) {
    // K fragments direct from global (B-operand: row=kv=j*16+lr, k=kk*32+g*8)
    short8 kf[2][4];
    #pragma unroll
    for (int kk = 0; kk < 2; ++kk)
      #pragma unroll
      for (int j = 0; j < 4; ++j)
        kf[kk][j] = *(const short8*)&Kb[(size_t)(t * 64 + j * 16 + lr) * DD + kk * 32 + g * 8];

    f32x4 sv[4];
    #pragma unroll
    for (int j = 0; j < 4; ++j) sv[j] = (f32x4){0.f, 0.f, 0.f, 0.f};
    #pragma unroll
    for (int kk = 0; kk < 2; ++kk)
      #pragma unroll
      for (int j = 0; j < 4; ++j)
        sv[j] = __builtin_amdgcn_mfma_f32_16x16x32_bf16(qf[kk], kf[kk][j], sv[j], 0, 0, 0);

    // V fragments issued before softmax: latency hides under the VALU chain
    short8 vf[2][4];
    #pragma unroll
    for (int kk = 0; kk < 2; ++kk)
      #pragma unroll
      for (int j = 0; j < 4; ++j)
        vf[kk][j] = *(const short8*)&Vtb[(size_t)(j * 16 + lr) * TT + t * 64 + kk * 32 + g * 8];

    if (t == qi) {  // diagonal tile only
      #pragma unroll
      for (int j = 0; j < 4; ++j)
        #pragma unroll
        for (int r = 0; r < 4; ++r) {
          int kv = t * 64 + j * 16 + lr;
          int qr = rowbase + g * 4 + r;
          if (kv > qr) sv[j][r] = -1e30f;
        }
    }
    #pragma unroll
    for (int r = 0; r < 4; ++r) {
      float mx = fmaxf(fmaxf(sv[0][r], sv[1][r]), fmaxf(sv[2][r], sv[3][r]));
      #pragma unroll
      for (int off = 1; off < 16; off <<= 1) mx = fmaxf(mx, __shfl_xor(mx, off, 64));
      float mnew = fmaxf(m_i[r], mx);
      float scl = exp2f(m_i[r] - mnew);
      m_i[r] = mnew;
      float rs = 0.f;
      #pragma unroll
      for (int j = 0; j < 4; ++j) {
        float p = exp2f(sv[j][r] - mnew);
        sv[j][r] = p;
        rs += p;
      }
      #pragma unroll
      for (int off = 1; off < 16; off <<= 1) rs += __shfl_xor(rs, off, 64);
      l_i[r] = l_i[r] * scl + rs;
      #pragma unroll
      for (int j = 0; j < 4; ++j) acc[j][r] *= scl;
    }
    // P -> per-wave LDS (in-wave ordering; no barrier), back as A-fragment
    #pragma unroll
    for (int j = 0; j < 4; ++j)
      #pragma unroll
      for (int r = 0; r < 4; ++r)
        Pw[wave][(g * 4 + r) * LDT + j * 16 + lr] = f2bf(sv[j][r]);
    #pragma unroll
    for (int kk = 0; kk < 2; ++kk) {
      short8 pf = *(const short8*)&Pw[wave][lr * LDT + kk * 32 + g * 8];
      #pragma unroll
      for (int j = 0; j < 4; ++j)
        acc[j] = __builtin_amdgcn_mfma_f32_16x16x32_bf16(pf, vf[kk][j], acc[j], 0, 0, 0);
    }
  }

  const int b = bh >> 4, h = bh & 15;
  #pragma unroll
  for (int r = 0; r < 4; ++r) {
    float inv = 1.0f / l_i[r];
    int qr = rowbase + g * 4 + r;
    size_t rowo = ((size_t)b * TT + qr) * CC + h * DD;
    #pragma unroll
    for (int j = 0; j < 4; ++j)
      aout[rowo + j * 16 + lr] = f2bf(acc[j][r] * inv);
  }
}

extern "C" void kernel_launch(void* const* d_in, const int* in_sizes, int n_in,
                              void* d_out, int out_size, void* d_ws, size_t ws_size,
                              hipStream_t stream) {
  const float* x    = (const float*)d_in[0];
  const float* wq   = (const float*)d_in[1];
  const float* wk   = (const float*)d_in[2];
  const float* wv   = (const float*)d_in[3];
  const float* wo   = (const float*)d_in[4];
  const float* cosb = (const float*)d_in[5];
  const float* sinb = (const float*)d_in[6];
  float* out = (float*)d_out;
  char* ws = (char*)d_ws;

  const size_t MB = 1u << 20;
  unsigned short* xb    = (unsigned short*)(ws);              //  8 MB [4096,1024]
  unsigned short* wqkvb = (unsigned short*)(ws + 8 * MB);     //  6 MB [3072,1024]
  unsigned short* wob   = (unsigned short*)(ws + 14 * MB);    //  2 MB [1024,1024]
  unsigned short* sqkv  = (unsigned short*)(ws + 16 * MB);    // 24 MB [4096,3072]
  unsigned short* qb2   = (unsigned short*)(ws + 40 * MB);    //  8 MB [B,H,T,D]
  unsigned short* kb2   = (unsigned short*)(ws + 48 * MB);    //  8 MB [B,H,T,D]
  unsigned short* vtb   = (unsigned short*)(ws + 56 * MB);    //  8 MB [B,H,D,T]
  unsigned short* aoutb = (unsigned short*)(ws + 64 * MB);    //  8 MB [4096,1024]

  cvt_f32_bf16<<<2048, 256, 0, stream>>>(x,  xb, 4194304);
  cvt_f32_bf16<<<1024, 256, 0, stream>>>(wq, wqkvb,           1048576);
  cvt_f32_bf16<<<1024, 256, 0, stream>>>(wk, wqkvb + 1048576, 1048576);
  cvt_f32_bf16<<<1024, 256, 0, stream>>>(wv, wqkvb + 2097152, 1048576);
  cvt_f32_bf16<<<1024, 256, 0, stream>>>(wo, wob,             1048576);

  gemm_bt<true><<<dim3(24, 32), 256, 0, stream>>>(xb, wqkvb, sqkv, 4096, 3072, 1024);
  rope_qk<<<8192, 256, 0, stream>>>(sqkv, cosb, sinb, qb2, kb2);
  vtrans<<<dim3(32, 32), 256, 0, stream>>>(sqkv, vtb);
  attn3<<<1024, 256, 0, stream>>>(qb2, kb2, vtb, aoutb);
  gemm_bt<false><<<dim3(8, 32), 256, 0, stream>>>(aoutb, wob, out, 4096, 1024, 1024);
}

// Round 4
// 230.132 us; speedup vs baseline: 1.0330x; 1.0330x over previous
//
#include <hip/hip_runtime.h>

typedef __attribute__((ext_vector_type(8))) short short8;
typedef __attribute__((ext_vector_type(4))) float f32x4;

#define BB 2
#define TT 2048
#define HH 16
#define DD 64
#define CC 1024

__device__ __forceinline__ unsigned short f2bf(float f) {
  union { float f; unsigned int u; } v; v.f = f;
  unsigned int r = v.u + 0x7fffu + ((v.u >> 16) & 1u);
  return (unsigned short)(r >> 16);
}
__device__ __forceinline__ float bf2f(unsigned short h) {
  union { unsigned int u; float f; } v; v.u = ((unsigned int)h) << 16; return v.f;
}

__global__ void cvt_f32_bf16(const float* __restrict__ in, unsigned short* __restrict__ out, int n) {
  int i = blockIdx.x * blockDim.x + threadIdx.x;
  int stride = gridDim.x * blockDim.x;
  for (; i < n; i += stride) out[i] = f2bf(in[i]);
}

// C = A @ B^T ; A [M,K] bf16, B [N,K] bf16, C [M,N] bf16 or f32
template<bool BF16OUT>
__global__ __launch_bounds__(256) void gemm_bt(const unsigned short* __restrict__ A,
                                               const unsigned short* __restrict__ B,
                                               void* __restrict__ Cv,
                                               int M, int N, int K) {
  constexpr int BK = 64, LDT = BK + 8;
  __shared__ unsigned short As[128 * LDT];
  __shared__ unsigned short Bs[128 * LDT];
  const int bm = blockIdx.y * 128, bn = blockIdx.x * 128;
  const int tid = threadIdx.x, wave = tid >> 6, lane = tid & 63;
  const int wm = (wave >> 1) * 64, wn = (wave & 1) * 64;
  const int g = lane >> 4, lr = lane & 15;
  f32x4 acc[4][4];
  #pragma unroll
  for (int i = 0; i < 4; ++i)
    #pragma unroll
    for (int j = 0; j < 4; ++j) acc[i][j] = (f32x4){0.f, 0.f, 0.f, 0.f};

  for (int k0 = 0; k0 < K; k0 += BK) {
    __syncthreads();
    #pragma unroll
    for (int p = 0; p < 4; ++p) {
      int r = p * 32 + (tid >> 3);
      int c = (tid & 7) * 8;
      *(short8*)&As[r * LDT + c] = *(const short8*)&A[(size_t)(bm + r) * K + k0 + c];
      *(short8*)&Bs[r * LDT + c] = *(const short8*)&B[(size_t)(bn + r) * K + k0 + c];
    }
    __syncthreads();
    #pragma unroll
    for (int kk = 0; kk < BK; kk += 32) {
      const int kb = kk + g * 8;
      short8 af[4], bf[4];
      #pragma unroll
      for (int i = 0; i < 4; ++i) {
        af[i] = *(const short8*)&As[(wm + i * 16 + lr) * LDT + kb];
        bf[i] = *(const short8*)&Bs[(wn + i * 16 + lr) * LDT + kb];
      }
      #pragma unroll
      for (int i = 0; i < 4; ++i)
        #pragma unroll
        for (int j = 0; j < 4; ++j)
          acc[i][j] = __builtin_amdgcn_mfma_f32_16x16x32_bf16(af[i], bf[j], acc[i][j], 0, 0, 0);
    }
  }
  #pragma unroll
  for (int i = 0; i < 4; ++i) {
    const int row0 = bm + wm + i * 16 + g * 4;
    #pragma unroll
    for (int j = 0; j < 4; ++j) {
      const int col = bn + wn + j * 16 + lr;
      #pragma unroll
      for (int r = 0; r < 4; ++r) {
        float v = acc[i][j][r];
        if (BF16OUT) ((unsigned short*)Cv)[(size_t)(row0 + r) * N + col] = f2bf(v);
        else         ((float*)Cv)[(size_t)(row0 + r) * N + col] = v;
      }
    }
  }
}

// qkv [B*T, 3*C] bf16 -> rope'd q (pre-scaled by log2e/sqrt(D)) and k, each [B,H,T,D] bf16
__global__ void rope_qk(const unsigned short* __restrict__ qkv,
                        const float* __restrict__ cosb, const float* __restrict__ sinb,
                        unsigned short* __restrict__ qo, unsigned short* __restrict__ ko) {
  int idx = blockIdx.x * blockDim.x + threadIdx.x;
  int d = idx & 31;
  int h = (idx >> 5) & 15;
  int t = (idx >> 9) & 2047;
  int b = idx >> 20;
  const unsigned short* row = qkv + (size_t)(b * TT + t) * (3 * CC);
  float c = cosb[t * DD + d], s = sinb[t * DD + d];
  float q1 = bf2f(row[h * DD + d]),      q2 = bf2f(row[h * DD + d + 32]);
  float k1 = bf2f(row[CC + h * DD + d]), k2 = bf2f(row[CC + h * DD + d + 32]);
  size_t o = (((size_t)(b * HH + h)) * TT + t) * DD + d;
  const float QS = 0.125f * 1.44269504089f;   // 1/sqrt(64) * log2(e): softmax in exp2 domain
  qo[o]      = f2bf(QS * (q1 * c - q2 * s));
  qo[o + 32] = f2bf(QS * (q2 * c + q1 * s));
  ko[o]      = f2bf(k1 * c - k2 * s);
  ko[o + 32] = f2bf(k2 * c + k1 * s);
}

// V slice of qkv -> vt [B,H,D,T] (transposed), LDS tiled, coalesced both sides
__global__ __launch_bounds__(256) void vtrans(const unsigned short* __restrict__ qkv,
                                              unsigned short* __restrict__ vt) {
  __shared__ unsigned short tile[64 * 72];
  const int bh = blockIdx.y, b = bh >> 4, h = bh & 15;
  const int t0 = blockIdx.x * 64;
  const int tid = threadIdx.x;
  const int r = tid >> 2, c0 = (tid & 3) * 16;
  const unsigned short* src = qkv + (size_t)(b * TT + t0 + r) * (3 * CC) + 2 * CC + h * DD + c0;
  *(short8*)&tile[r * 72 + c0]     = *(const short8*)src;
  *(short8*)&tile[r * 72 + c0 + 8] = *(const short8*)(src + 8);
  __syncthreads();
  short8 o0, o1;
  #pragma unroll
  for (int e = 0; e < 8; ++e) {
    ((unsigned short*)&o0)[e] = tile[(c0 + e) * 72 + r];
    ((unsigned short*)&o1)[e] = tile[(c0 + 8 + e) * 72 + r];
  }
  size_t dst = ((size_t)(bh * DD + r)) * TT + t0 + c0;
  *(short8*)&vt[dst]     = o0;
  *(short8*)&vt[dst + 8] = o1;
}

// Flash attention, causal, barrier-free, REGISTER DOUBLE-BUFFERED K/V prefetch.
// 1024 blocks x 4 independent waves, 16 q-rows/wave. K/V direct global->VGPR,
// next tile's 16 fragment loads issued before current tile's compute.
// __launch_bounds__(256,2): allow ~256 VGPR so all 32 in-flight loads have homes.
__global__ __launch_bounds__(256, 2) void attn4(const unsigned short* __restrict__ qb,
                                                const unsigned short* __restrict__ kb,
                                                const unsigned short* __restrict__ vt,
                                                unsigned short* __restrict__ aout) {
  constexpr int LDT = 72;
  __shared__ unsigned short Pw[4][16 * LDT];
  const int L = blockIdx.x;
  const int xcd = L & 7, m = L >> 3;
  const int bh = xcd * 4 + (m & 3);           // XCD c owns heads 4c..4c+3 (K+V = 2MB in L2)
  const int qi = 31 - (m >> 2);               // heavy q-tiles dispatch first
  const int qbase = qi * 64;
  const int tid = threadIdx.x, wave = tid >> 6, lane = tid & 63;
  const int g = lane >> 4, lr = lane & 15;
  const unsigned short* Qb  = qb + (size_t)bh * TT * DD;
  const unsigned short* Kb  = kb + (size_t)bh * TT * DD;
  const unsigned short* Vtb = vt + (size_t)bh * DD * TT;
  const int rowbase = qbase + wave * 16;

  short8 qf[2];
  #pragma unroll
  for (int kk = 0; kk < 2; ++kk)
    qf[kk] = *(const short8*)&Qb[(size_t)(rowbase + lr) * DD + kk * 32 + g * 8];

  f32x4 acc[4];
  float m_i[4], l_i[4];
  #pragma unroll
  for (int j = 0; j < 4; ++j) acc[j] = (f32x4){0.f, 0.f, 0.f, 0.f};
  #pragma unroll
  for (int r = 0; r < 4; ++r) { m_i[r] = -1e30f; l_i[r] = 0.f; }

  short8 kA[2][4], vA[2][4], kB[2][4], vB[2][4];

#define PRE(KF, VF, TI)                                                                  \
  {                                                                                      \
    const int tt = ((TI) <= qi) ? (TI) : qi; /* clamp: redundant reload, always valid */ \
    _Pragma("unroll")                                                                    \
    for (int kk = 0; kk < 2; ++kk)                                                       \
      _Pragma("unroll")                                                                  \
      for (int j = 0; j < 4; ++j) {                                                      \
        KF[kk][j] = *(const short8*)&Kb[(size_t)(tt * 64 + j * 16 + lr) * DD + kk * 32 + g * 8]; \
        VF[kk][j] = *(const short8*)&Vtb[(size_t)(j * 16 + lr) * TT + tt * 64 + kk * 32 + g * 8]; \
      }                                                                                  \
  }

#define COMP(KF, VF, TI)                                                                 \
  {                                                                                      \
    const int t_ = (TI);                                                                 \
    f32x4 sv[4];                                                                         \
    _Pragma("unroll")                                                                    \
    for (int j = 0; j < 4; ++j) sv[j] = (f32x4){0.f, 0.f, 0.f, 0.f};                     \
    _Pragma("unroll")                                                                    \
    for (int kk = 0; kk < 2; ++kk)                                                       \
      _Pragma("unroll")                                                                  \
      for (int j = 0; j < 4; ++j)                                                        \
        sv[j] = __builtin_amdgcn_mfma_f32_16x16x32_bf16(qf[kk], KF[kk][j], sv[j], 0, 0, 0); \
    if (t_ == qi) { /* diagonal tile mask */                                             \
      _Pragma("unroll")                                                                  \
      for (int j = 0; j < 4; ++j)                                                        \
        _Pragma("unroll")                                                                \
        for (int r = 0; r < 4; ++r) {                                                    \
          int kv = t_ * 64 + j * 16 + lr;                                                \
          int qr = rowbase + g * 4 + r;                                                  \
          if (kv > qr) sv[j][r] = -1e30f;                                                \
        }                                                                                \
    }                                                                                    \
    _Pragma("unroll")                                                                    \
    for (int r = 0; r < 4; ++r) {                                                        \
      float mx = fmaxf(fmaxf(sv[0][r], sv[1][r]), fmaxf(sv[2][r], sv[3][r]));            \
      _Pragma("unroll")                                                                  \
      for (int off = 1; off < 16; off <<= 1) mx = fmaxf(mx, __shfl_xor(mx, off, 64));    \
      float mnew = fmaxf(m_i[r], mx);                                                    \
      float scl = exp2f(m_i[r] - mnew);                                                  \
      m_i[r] = mnew;                                                                     \
      float rs = 0.f;                                                                    \
      _Pragma("unroll")                                                                  \
      for (int j = 0; j < 4; ++j) {                                                      \
        float p = exp2f(sv[j][r] - mnew);                                                \
        sv[j][r] = p;                                                                    \
        rs += p;                                                                         \
      }                                                                                  \
      _Pragma("unroll")                                                                  \
      for (int off = 1; off < 16; off <<= 1) rs += __shfl_xor(rs, off, 64);              \
      l_i[r] = l_i[r] * scl + rs;                                                        \
      _Pragma("unroll")                                                                  \
      for (int j = 0; j < 4; ++j) acc[j][r] *= scl;                                      \
    }                                                                                    \
    _Pragma("unroll")                                                                    \
    for (int j = 0; j < 4; ++j)                                                          \
      _Pragma("unroll")                                                                  \
      for (int r = 0; r < 4; ++r)                                                        \
        Pw[wave][(g * 4 + r) * LDT + j * 16 + lr] = f2bf(sv[j][r]);                      \
    _Pragma("unroll")                                                                    \
    for (int kk = 0; kk < 2; ++kk) {                                                     \
      short8 pf = *(const short8*)&Pw[wave][lr * LDT + kk * 32 + g * 8];                 \
      _Pragma("unroll")                                                                  \
      for (int j = 0; j < 4; ++j)                                                        \
        acc[j] = __builtin_amdgcn_mfma_f32_16x16x32_bf16(pf, VF[kk][j], acc[j], 0, 0, 0); \
    }                                                                                    \
  }

  PRE(kA, vA, 0);
  for (int t = 0;; t += 2) {
    PRE(kB, vB, t + 1);
    COMP(kA, vA, t);
    if (t + 1 > qi) break;
    PRE(kA, vA, t + 2);
    COMP(kB, vB, t + 1);
    if (t + 2 > qi) break;
  }
#undef PRE
#undef COMP

  const int b = bh >> 4, h = bh & 15;
  #pragma unroll
  for (int r = 0; r < 4; ++r) {
    float inv = 1.0f / l_i[r];
    int qr = rowbase + g * 4 + r;
    size_t rowo = ((size_t)b * TT + qr) * CC + h * DD;
    #pragma unroll
    for (int j = 0; j < 4; ++j)
      aout[rowo + j * 16 + lr] = f2bf(acc[j][r] * inv);
  }
}

extern "C" void kernel_launch(void* const* d_in, const int* in_sizes, int n_in,
                              void* d_out, int out_size, void* d_ws, size_t ws_size,
                              hipStream_t stream) {
  const float* x    = (const float*)d_in[0];
  const float* wq   = (const float*)d_in[1];
  const float* wk   = (const float*)d_in[2];
  const float* wv   = (const float*)d_in[3];
  const float* wo   = (const float*)d_in[4];
  const float* cosb = (const float*)d_in[5];
  const float* sinb = (const float*)d_in[6];
  float* out = (float*)d_out;
  char* ws = (char*)d_ws;

  const size_t MB = 1u << 20;
  unsigned short* xb    = (unsigned short*)(ws);              //  8 MB [4096,1024]
  unsigned short* wqkvb = (unsigned short*)(ws + 8 * MB);     //  6 MB [3072,1024]
  unsigned short* wob   = (unsigned short*)(ws + 14 * MB);    //  2 MB [1024,1024]
  unsigned short* sqkv  = (unsigned short*)(ws + 16 * MB);    // 24 MB [4096,3072]
  unsigned short* qb2   = (unsigned short*)(ws + 40 * MB);    //  8 MB [B,H,T,D]
  unsigned short* kb2   = (unsigned short*)(ws + 48 * MB);    //  8 MB [B,H,T,D]
  unsigned short* vtb   = (unsigned short*)(ws + 56 * MB);    //  8 MB [B,H,D,T]
  unsigned short* aoutb = (unsigned short*)(ws + 64 * MB);    //  8 MB [4096,1024]

  cvt_f32_bf16<<<2048, 256, 0, stream>>>(x,  xb, 4194304);
  cvt_f32_bf16<<<1024, 256, 0, stream>>>(wq, wqkvb,           1048576);
  cvt_f32_bf16<<<1024, 256, 0, stream>>>(wk, wqkvb + 1048576, 1048576);
  cvt_f32_bf16<<<1024, 256, 0, stream>>>(wv, wqkvb + 2097152, 1048576);
  cvt_f32_bf16<<<1024, 256, 0, stream>>>(wo, wob,             1048576);

  gemm_bt<true><<<dim3(24, 32), 256, 0, stream>>>(xb, wqkvb, sqkv, 4096, 3072, 1024);
  rope_qk<<<8192, 256, 0, stream>>>(sqkv, cosb, sinb, qb2, kb2);
  vtrans<<<dim3(32, 32), 256, 0, stream>>>(sqkv, vtb);
  attn4<<<1024, 256, 0, stream>>>(qb2, kb2, vtb, aoutb);
  gemm_bt<false><<<dim3(8, 32), 256, 0, stream>>>(aoutb, wob, out, 4096, 1024, 1024);
}

// Round 5
// 157.136 us; speedup vs baseline: 1.5128x; 1.4645x over previous
//
#include <hip/hip_runtime.h>

typedef __attribute__((ext_vector_type(8))) short short8;
typedef __attribute__((ext_vector_type(4))) float f32x4;

#define BB 2
#define TT 2048
#define HH 16
#define DD 64
#define CC 1024

__device__ __forceinline__ unsigned short f2bf(float f) {
  union { float f; unsigned int u; } v; v.f = f;
  unsigned int r = v.u + 0x7fffu + ((v.u >> 16) & 1u);
  return (unsigned short)(r >> 16);
}
__device__ __forceinline__ float bf2f(unsigned short h) {
  union { unsigned int u; float f; } v; v.u = ((unsigned int)h) << 16; return v.f;
}

__global__ void cvt_f32_bf16(const float* __restrict__ in, unsigned short* __restrict__ out, int n) {
  int i = blockIdx.x * blockDim.x + threadIdx.x;
  int stride = gridDim.x * blockDim.x;
  for (; i < n; i += stride) out[i] = f2bf(in[i]);
}

// C = A @ B^T ; m97 structure: global_load_lds width-16, linear LDS, 2 barriers/K-step.
template<bool BF16OUT>
__global__ __launch_bounds__(256) void gemm_bt(const unsigned short* __restrict__ A,
                                               const unsigned short* __restrict__ B,
                                               void* __restrict__ Cv,
                                               int M, int N, int K) {
  __shared__ unsigned short As[128 * 64];   // linear: global_load_lds dest must be contiguous
  __shared__ unsigned short Bs[128 * 64];
  const int bm = blockIdx.y * 128, bn = blockIdx.x * 128;
  const int tid = threadIdx.x, wave = tid >> 6, lane = tid & 63;
  const int wm = (wave >> 1) * 64, wn = (wave & 1) * 64;
  const int g = lane >> 4, lr = lane & 15;
  f32x4 acc[4][4];
  #pragma unroll
  for (int i = 0; i < 4; ++i)
    #pragma unroll
    for (int j = 0; j < 4; ++j) acc[i][j] = (f32x4){0.f, 0.f, 0.f, 0.f};

  const int srow = lane >> 3, scol = (lane & 7) * 8;   // staging: 8 rows/chunk, 16B/lane

  for (int k0 = 0; k0 < K; k0 += 64) {
    __syncthreads();   // previous compute's reads complete before overwrite
    #pragma unroll
    for (int c = 0; c < 4; ++c) {
      const int chunk = wave * 4 + c;          // 16 chunks of 8 rows each
      const int row = chunk * 8 + srow;
      __builtin_amdgcn_global_load_lds(
        (const __attribute__((address_space(1))) void*)&A[(size_t)(bm + row) * K + k0 + scol],
        (__attribute__((address_space(3))) void*)&As[chunk * 512], 16, 0, 0);
      __builtin_amdgcn_global_load_lds(
        (const __attribute__((address_space(1))) void*)&B[(size_t)(bn + row) * K + k0 + scol],
        (__attribute__((address_space(3))) void*)&Bs[chunk * 512], 16, 0, 0);
    }
    __syncthreads();   // compiler drains vmcnt(0) per-wave before barrier: staging visible
    #pragma unroll
    for (int kk = 0; kk < 64; kk += 32) {
      const int kb = kk + g * 8;
      short8 af[4], bf[4];
      #pragma unroll
      for (int i = 0; i < 4; ++i) {
        af[i] = *(const short8*)&As[(wm + i * 16 + lr) * 64 + kb];
        bf[i] = *(const short8*)&Bs[(wn + i * 16 + lr) * 64 + kb];
      }
      __builtin_amdgcn_s_setprio(1);
      #pragma unroll
      for (int i = 0; i < 4; ++i)
        #pragma unroll
        for (int j = 0; j < 4; ++j)
          acc[i][j] = __builtin_amdgcn_mfma_f32_16x16x32_bf16(af[i], bf[j], acc[i][j], 0, 0, 0);
      __builtin_amdgcn_s_setprio(0);
    }
  }
  #pragma unroll
  for (int i = 0; i < 4; ++i) {
    const int row0 = bm + wm + i * 16 + g * 4;
    #pragma unroll
    for (int j = 0; j < 4; ++j) {
      const int col = bn + wn + j * 16 + lr;
      #pragma unroll
      for (int r = 0; r < 4; ++r) {
        float v = acc[i][j][r];
        if (BF16OUT) ((unsigned short*)Cv)[(size_t)(row0 + r) * N + col] = f2bf(v);
        else         ((float*)Cv)[(size_t)(row0 + r) * N + col] = v;
      }
    }
  }
}

// qkv [B*T, 3*C] bf16 -> rope'd q (pre-scaled by log2e/sqrt(D)) and k, each [B,H,T,D] bf16
__global__ void rope_qk(const unsigned short* __restrict__ qkv,
                        const float* __restrict__ cosb, const float* __restrict__ sinb,
                        unsigned short* __restrict__ qo, unsigned short* __restrict__ ko) {
  int idx = blockIdx.x * blockDim.x + threadIdx.x;
  int d = idx & 31;
  int h = (idx >> 5) & 15;
  int t = (idx >> 9) & 2047;
  int b = idx >> 20;
  const unsigned short* row = qkv + (size_t)(b * TT + t) * (3 * CC);
  float c = cosb[t * DD + d], s = sinb[t * DD + d];
  float q1 = bf2f(row[h * DD + d]),      q2 = bf2f(row[h * DD + d + 32]);
  float k1 = bf2f(row[CC + h * DD + d]), k2 = bf2f(row[CC + h * DD + d + 32]);
  size_t o = (((size_t)(b * HH + h)) * TT + t) * DD + d;
  const float QS = 0.125f * 1.44269504089f;   // 1/sqrt(64) * log2(e): softmax in exp2 domain
  qo[o]      = f2bf(QS * (q1 * c - q2 * s));
  qo[o + 32] = f2bf(QS * (q2 * c + q1 * s));
  ko[o]      = f2bf(k1 * c - k2 * s);
  ko[o + 32] = f2bf(k2 * c + k1 * s);
}

// V slice of qkv -> vt [B,H,D,T] (transposed), LDS tiled, coalesced both sides
__global__ __launch_bounds__(256) void vtrans(const unsigned short* __restrict__ qkv,
                                              unsigned short* __restrict__ vt) {
  __shared__ unsigned short tile[64 * 72];
  const int bh = blockIdx.y, b = bh >> 4, h = bh & 15;
  const int t0 = blockIdx.x * 64;
  const int tid = threadIdx.x;
  const int r = tid >> 2, c0 = (tid & 3) * 16;
  const unsigned short* src = qkv + (size_t)(b * TT + t0 + r) * (3 * CC) + 2 * CC + h * DD + c0;
  *(short8*)&tile[r * 72 + c0]     = *(const short8*)src;
  *(short8*)&tile[r * 72 + c0 + 8] = *(const short8*)(src + 8);
  __syncthreads();
  short8 o0, o1;
  #pragma unroll
  for (int e = 0; e < 8; ++e) {
    ((unsigned short*)&o0)[e] = tile[(c0 + e) * 72 + r];
    ((unsigned short*)&o1)[e] = tile[(c0 + 8 + e) * 72 + r];
  }
  size_t dst = ((size_t)(bh * DD + r)) * TT + t0 + c0;
  *(short8*)&vt[dst]     = o0;
  *(short8*)&vt[dst + 8] = o1;
}

// Flash attention, causal. K/V staged via global_load_lds (zero VGPR cost, true DMA
// prefetch), LDS double-buffered, 2-phase: stage(t+1) -> compute(t) -> barrier.
// LDS is linear (gload_lds requires it); 16-way read conflict fixed by both-sides XOR
// swizzle: inverse-swizzled GLOBAL source + swizzled ds_read (rule #21).
__global__ __launch_bounds__(256, 3) void attn5(const unsigned short* __restrict__ qb,
                                                const unsigned short* __restrict__ kb,
                                                const unsigned short* __restrict__ vt,
                                                unsigned short* __restrict__ aout) {
  __shared__ unsigned short Kbuf[2][64 * 64];   // [kv][d], swizzled storage
  __shared__ unsigned short Vbuf[2][64 * 64];   // [d][kv], swizzled storage
  __shared__ unsigned short Pw[4][16 * 72];     // per-wave P staging (padded, wave-private)
  const int L = blockIdx.x;
  const int xcd = L & 7, m = L >> 3;
  const int bh = xcd * 4 + (m & 3);           // XCD c owns heads 4c..4c+3 (K+V 2MB in its L2)
  const int qi = 31 - (m >> 2);               // heavy q-tiles dispatch first
  const int qbase = qi * 64;
  const int tid = threadIdx.x, wave = tid >> 6, lane = tid & 63;
  const int g = lane >> 4, lr = lane & 15;
  const unsigned short* Qb  = qb + (size_t)bh * TT * DD;
  const unsigned short* Kb  = kb + (size_t)bh * TT * DD;
  const unsigned short* Vtb = vt + (size_t)bh * DD * TT;
  const int rowbase = qbase + wave * 16;

  short8 qf[2];
  #pragma unroll
  for (int kk = 0; kk < 2; ++kk)
    qf[kk] = *(const short8*)&Qb[(size_t)(rowbase + lr) * DD + kk * 32 + g * 8];

  f32x4 acc[4];
  float m_i[4], l_i[4];
  #pragma unroll
  for (int j = 0; j < 4; ++j) acc[j] = (f32x4){0.f, 0.f, 0.f, 0.f};
  #pragma unroll
  for (int r = 0; r < 4; ++r) { m_i[r] = -1e30f; l_i[r] = 0.f; }

  // Staging: 8 chunks of 1KB per tile (K and V each); wave w stages chunks 2w, 2w+1.
  // chunk c, lane l -> row = c*8 + l/8. LDS linear dest; source col pre-XOR'd so that
  // LDS[row][ch] = G[row][ch ^ ((row&7)<<3)] (halfword units).
  const int srow8 = lane >> 3;
  const int ssw_base = (lane & 7) * 8;   // halfword col before swizzle

#define STAGE_KV(BUF, TI)                                                                   \
  {                                                                                         \
    const int tt = (TI);                                                                    \
    _Pragma("unroll")                                                                       \
    for (int c = 0; c < 2; ++c) {                                                           \
      const int chunk = wave * 2 + c;                                                       \
      const int row = chunk * 8 + srow8;                                                    \
      const int sw = ssw_base ^ ((row & 7) << 3);                                           \
      __builtin_amdgcn_global_load_lds(                                                     \
        (const __attribute__((address_space(1))) void*)&Kb[(size_t)(tt * 64 + row) * DD + sw], \
        (__attribute__((address_space(3))) void*)&Kbuf[BUF][chunk * 512], 16, 0, 0);        \
      __builtin_amdgcn_global_load_lds(                                                     \
        (const __attribute__((address_space(1))) void*)&Vtb[(size_t)row * TT + tt * 64 + sw], \
        (__attribute__((address_space(3))) void*)&Vbuf[BUF][chunk * 512], 16, 0, 0);        \
    }                                                                                       \
  }

  STAGE_KV(0, 0);
  __syncthreads();           // vmcnt(0) drained per-wave by compiler before barrier

  for (int t = 0; t <= qi; ++t) {
    const int cur = t & 1;
    if (t < qi) STAGE_KV(cur ^ 1, t + 1);    // fire-and-forget DMA; lands before next barrier

    // ---- S = Q K^T ----  swizzled read: row=j*16+lr, hw col = (kk*32+g*8) ^ ((lr&7)<<3)
    f32x4 sv[4];
    #pragma unroll
    for (int j = 0; j < 4; ++j) sv[j] = (f32x4){0.f, 0.f, 0.f, 0.f};
    #pragma unroll
    for (int kk = 0; kk < 2; ++kk) {
      const int swc = (kk * 32 + g * 8) ^ ((lr & 7) << 3);
      short8 kf[4];
      #pragma unroll
      for (int j = 0; j < 4; ++j)
        kf[j] = *(const short8*)&Kbuf[cur][(j * 16 + lr) * 64 + swc];
      __builtin_amdgcn_s_setprio(1);
      #pragma unroll
      for (int j = 0; j < 4; ++j)
        sv[j] = __builtin_amdgcn_mfma_f32_16x16x32_bf16(qf[kk], kf[j], sv[j], 0, 0, 0);
      __builtin_amdgcn_s_setprio(0);
    }

    if (t == qi) {  // diagonal tile mask
      #pragma unroll
      for (int j = 0; j < 4; ++j)
        #pragma unroll
        for (int r = 0; r < 4; ++r) {
          int kv = t * 64 + j * 16 + lr;
          int qr = rowbase + g * 4 + r;
          if (kv > qr) sv[j][r] = -1e30f;
        }
    }
    // ---- online softmax (q-row g*4+r; its 16 cols live in one 16-lane group) ----
    #pragma unroll
    for (int r = 0; r < 4; ++r) {
      float mx = fmaxf(fmaxf(sv[0][r], sv[1][r]), fmaxf(sv[2][r], sv[3][r]));
      #pragma unroll
      for (int off = 1; off < 16; off <<= 1) mx = fmaxf(mx, __shfl_xor(mx, off, 64));
      float mnew = fmaxf(m_i[r], mx);
      float scl = exp2f(m_i[r] - mnew);
      m_i[r] = mnew;
      float rs = 0.f;
      #pragma unroll
      for (int j = 0; j < 4; ++j) {
        float p = exp2f(sv[j][r] - mnew);
        sv[j][r] = p;
        rs += p;
      }
      #pragma unroll
      for (int off = 1; off < 16; off <<= 1) rs += __shfl_xor(rs, off, 64);
      l_i[r] = l_i[r] * scl + rs;
      #pragma unroll
      for (int j = 0; j < 4; ++j) acc[j][r] *= scl;
    }
    // ---- P -> wave-private LDS, back as A-fragment; PV ----
    #pragma unroll
    for (int j = 0; j < 4; ++j)
      #pragma unroll
      for (int r = 0; r < 4; ++r)
        Pw[wave][(g * 4 + r) * 72 + j * 16 + lr] = f2bf(sv[j][r]);
    #pragma unroll
    for (int kk = 0; kk < 2; ++kk) {
      short8 pf = *(const short8*)&Pw[wave][lr * 72 + kk * 32 + g * 8];
      const int swc = (kk * 32 + g * 8) ^ ((lr & 7) << 3);
      short8 vf[4];
      #pragma unroll
      for (int j = 0; j < 4; ++j)
        vf[j] = *(const short8*)&Vbuf[cur][(j * 16 + lr) * 64 + swc];
      __builtin_amdgcn_s_setprio(1);
      #pragma unroll
      for (int j = 0; j < 4; ++j)
        acc[j] = __builtin_amdgcn_mfma_f32_16x16x32_bf16(pf, vf[j], acc[j], 0, 0, 0);
      __builtin_amdgcn_s_setprio(0);
    }
    __syncthreads();   // drains this wave's staging vmcnt + all waves' reads of buf[cur]
  }
#undef STAGE_KV

  const int b = bh >> 4, h = bh & 15;
  #pragma unroll
  for (int r = 0; r < 4; ++r) {
    float inv = 1.0f / l_i[r];
    int qr = rowbase + g * 4 + r;
    size_t rowo = ((size_t)b * TT + qr) * CC + h * DD;
    #pragma unroll
    for (int j = 0; j < 4; ++j)
      aout[rowo + j * 16 + lr] = f2bf(acc[j][r] * inv);
  }
}

extern "C" void kernel_launch(void* const* d_in, const int* in_sizes, int n_in,
                              void* d_out, int out_size, void* d_ws, size_t ws_size,
                              hipStream_t stream) {
  const float* x    = (const float*)d_in[0];
  const float* wq   = (const float*)d_in[1];
  const float* wk   = (const float*)d_in[2];
  const float* wv   = (const float*)d_in[3];
  const float* wo   = (const float*)d_in[4];
  const float* cosb = (const float*)d_in[5];
  const float* sinb = (const float*)d_in[6];
  float* out = (float*)d_out;
  char* ws = (char*)d_ws;

  const size_t MB = 1u << 20;
  unsigned short* xb    = (unsigned short*)(ws);              //  8 MB [4096,1024]
  unsigned short* wqkvb = (unsigned short*)(ws + 8 * MB);     //  6 MB [3072,1024]
  unsigned short* wob   = (unsigned short*)(ws + 14 * MB);    //  2 MB [1024,1024]
  unsigned short* sqkv  = (unsigned short*)(ws + 16 * MB);    // 24 MB [4096,3072]
  unsigned short* qb2   = (unsigned short*)(ws + 40 * MB);    //  8 MB [B,H,T,D]
  unsigned short* kb2   = (unsigned short*)(ws + 48 * MB);    //  8 MB [B,H,T,D]
  unsigned short* vtb   = (unsigned short*)(ws + 56 * MB);    //  8 MB [B,H,D,T]
  unsigned short* aoutb = (unsigned short*)(ws + 64 * MB);    //  8 MB [4096,1024]

  cvt_f32_bf16<<<2048, 256, 0, stream>>>(x,  xb, 4194304);
  cvt_f32_bf16<<<1024, 256, 0, stream>>>(wq, wqkvb,           1048576);
  cvt_f32_bf16<<<1024, 256, 0, stream>>>(wk, wqkvb + 1048576, 1048576);
  cvt_f32_bf16<<<1024, 256, 0, stream>>>(wv, wqkvb + 2097152, 1048576);
  cvt_f32_bf16<<<1024, 256, 0, stream>>>(wo, wob,             1048576);

  gemm_bt<true><<<dim3(24, 32), 256, 0, stream>>>(xb, wqkvb, sqkv, 4096, 3072, 1024);
  rope_qk<<<8192, 256, 0, stream>>>(sqkv, cosb, sinb, qb2, kb2);
  vtrans<<<dim3(32, 32), 256, 0, stream>>>(sqkv, vtb);
  attn5<<<1024, 256, 0, stream>>>(qb2, kb2, vtb, aoutb);
  gemm_bt<false><<<dim3(8, 32), 256, 0, stream>>>(aoutb, wob, out, 4096, 1024, 1024);
}

// Round 6
// 134.126 us; speedup vs baseline: 1.7723x; 1.1716x over previous
//
#include <hip/hip_runtime.h>

typedef __attribute__((ext_vector_type(8))) short short8;
typedef __attribute__((ext_vector_type(4))) float f32x4;

#define BB 2
#define TT 2048
#define HH 16
#define DD 64
#define CC 1024

__device__ __forceinline__ unsigned short f2bf(float f) {
  union { float f; unsigned int u; } v; v.f = f;
  unsigned int r = v.u + 0x7fffu + ((v.u >> 16) & 1u);
  return (unsigned short)(r >> 16);
}
__device__ __forceinline__ float bf2f(unsigned short h) {
  union { unsigned int u; float f; } v; v.u = ((unsigned int)h) << 16; return v.f;
}
__device__ __forceinline__ unsigned int cvtpk(float lo, float hi) {
  unsigned int r;
  asm("v_cvt_pk_bf16_f32 %0, %1, %2" : "=v"(r) : "v"(lo), "v"(hi));
  return r;   // D[15:0]=bf16(lo), D[31:16]=bf16(hi)
}

__global__ void cvt_f32_bf16(const float* __restrict__ in, unsigned short* __restrict__ out, int n) {
  int i = blockIdx.x * blockDim.x + threadIdx.x;
  int stride = gridDim.x * blockDim.x;
  for (; i < n; i += stride) out[i] = f2bf(in[i]);
}

// C = A @ B^T ; m97 structure: global_load_lds width-16, linear LDS, 2 barriers/K-step.
template<bool BF16OUT>
__global__ __launch_bounds__(256) void gemm_bt(const unsigned short* __restrict__ A,
                                               const unsigned short* __restrict__ B,
                                               void* __restrict__ Cv,
                                               int M, int N, int K) {
  __shared__ unsigned short As[128 * 64];
  __shared__ unsigned short Bs[128 * 64];
  const int bm = blockIdx.y * 128, bn = blockIdx.x * 128;
  const int tid = threadIdx.x, wave = tid >> 6, lane = tid & 63;
  const int wm = (wave >> 1) * 64, wn = (wave & 1) * 64;
  const int g = lane >> 4, lr = lane & 15;
  f32x4 acc[4][4];
  #pragma unroll
  for (int i = 0; i < 4; ++i)
    #pragma unroll
    for (int j = 0; j < 4; ++j) acc[i][j] = (f32x4){0.f, 0.f, 0.f, 0.f};

  const int srow = lane >> 3, scol = (lane & 7) * 8;

  for (int k0 = 0; k0 < K; k0 += 64) {
    __syncthreads();
    #pragma unroll
    for (int c = 0; c < 4; ++c) {
      const int chunk = wave * 4 + c;
      const int row = chunk * 8 + srow;
      __builtin_amdgcn_global_load_lds(
        (const __attribute__((address_space(1))) void*)&A[(size_t)(bm + row) * K + k0 + scol],
        (__attribute__((address_space(3))) void*)&As[chunk * 512], 16, 0, 0);
      __builtin_amdgcn_global_load_lds(
        (const __attribute__((address_space(1))) void*)&B[(size_t)(bn + row) * K + k0 + scol],
        (__attribute__((address_space(3))) void*)&Bs[chunk * 512], 16, 0, 0);
    }
    __syncthreads();
    #pragma unroll
    for (int kk = 0; kk < 64; kk += 32) {
      const int kb = kk + g * 8;
      short8 af[4], bf[4];
      #pragma unroll
      for (int i = 0; i < 4; ++i) {
        af[i] = *(const short8*)&As[(wm + i * 16 + lr) * 64 + kb];
        bf[i] = *(const short8*)&Bs[(wn + i * 16 + lr) * 64 + kb];
      }
      __builtin_amdgcn_s_setprio(1);
      #pragma unroll
      for (int i = 0; i < 4; ++i)
        #pragma unroll
        for (int j = 0; j < 4; ++j)
          acc[i][j] = __builtin_amdgcn_mfma_f32_16x16x32_bf16(af[i], bf[j], acc[i][j], 0, 0, 0);
      __builtin_amdgcn_s_setprio(0);
    }
  }
  #pragma unroll
  for (int i = 0; i < 4; ++i) {
    const int row0 = bm + wm + i * 16 + g * 4;
    #pragma unroll
    for (int j = 0; j < 4; ++j) {
      const int col = bn + wn + j * 16 + lr;
      #pragma unroll
      for (int r = 0; r < 4; ++r) {
        float v = acc[i][j][r];
        if (BF16OUT) ((unsigned short*)Cv)[(size_t)(row0 + r) * N + col] = f2bf(v);
        else         ((float*)Cv)[(size_t)(row0 + r) * N + col] = v;
      }
    }
  }
}

// qkv [B*T, 3*C] bf16 -> rope'd q (pre-scaled by log2e/sqrt(D)) and k, each [B,H,T,D] bf16
__global__ void rope_qk(const unsigned short* __restrict__ qkv,
                        const float* __restrict__ cosb, const float* __restrict__ sinb,
                        unsigned short* __restrict__ qo, unsigned short* __restrict__ ko) {
  int idx = blockIdx.x * blockDim.x + threadIdx.x;
  int d = idx & 31;
  int h = (idx >> 5) & 15;
  int t = (idx >> 9) & 2047;
  int b = idx >> 20;
  const unsigned short* row = qkv + (size_t)(b * TT + t) * (3 * CC);
  float c = cosb[t * DD + d], s = sinb[t * DD + d];
  float q1 = bf2f(row[h * DD + d]),      q2 = bf2f(row[h * DD + d + 32]);
  float k1 = bf2f(row[CC + h * DD + d]), k2 = bf2f(row[CC + h * DD + d + 32]);
  size_t o = (((size_t)(b * HH + h)) * TT + t) * DD + d;
  const float QS = 0.125f * 1.44269504089f;   // 1/sqrt(64) * log2(e): softmax in exp2 domain
  qo[o]      = f2bf(QS * (q1 * c - q2 * s));
  qo[o + 32] = f2bf(QS * (q2 * c + q1 * s));
  ko[o]      = f2bf(k1 * c - k2 * s);
  ko[o + 32] = f2bf(k2 * c + k1 * s);
}

// V slice of qkv -> vt [B,H,D,T] (transposed), LDS tiled, coalesced both sides
__global__ __launch_bounds__(256) void vtrans(const unsigned short* __restrict__ qkv,
                                              unsigned short* __restrict__ vt) {
  __shared__ unsigned short tile[64 * 72];
  const int bh = blockIdx.y, b = bh >> 4, h = bh & 15;
  const int t0 = blockIdx.x * 64;
  const int tid = threadIdx.x;
  const int r = tid >> 2, c0 = (tid & 3) * 16;
  const unsigned short* src = qkv + (size_t)(b * TT + t0 + r) * (3 * CC) + 2 * CC + h * DD + c0;
  *(short8*)&tile[r * 72 + c0]     = *(const short8*)src;
  *(short8*)&tile[r * 72 + c0 + 8] = *(const short8*)(src + 8);
  __syncthreads();
  short8 o0, o1;
  #pragma unroll
  for (int e = 0; e < 8; ++e) {
    ((unsigned short*)&o0)[e] = tile[(c0 + e) * 72 + r];
    ((unsigned short*)&o1)[e] = tile[(c0 + 8 + e) * 72 + r];
  }
  size_t dst = ((size_t)(bh * DD + r)) * TT + t0 + c0;
  *(short8*)&vt[dst]     = o0;
  *(short8*)&vt[dst + 8] = o1;
}

// Flash attention, causal. global_load_lds double-buffered staging (round 5) +
// SWAPPED-OPERAND QK^T: S^T = mfma(K,Q) puts each lane's full q-row (64 kv) in
// register -> lane-local softmax (2 shfl instead of 32), vectorized P writes
// (4x ds_write_b64 via cvt_pk), O accumulated transposed (O^T = mfma(V^T, P^T)),
// vectorized output stores.
__global__ __launch_bounds__(256, 3) void attn6(const unsigned short* __restrict__ qb,
                                                const unsigned short* __restrict__ kb,
                                                const unsigned short* __restrict__ vt,
                                                unsigned short* __restrict__ aout) {
  __shared__ unsigned short Kbuf[2][64 * 64];   // [kv][d], swizzled storage
  __shared__ unsigned short Vbuf[2][64 * 64];   // [d][kv], swizzled storage
  __shared__ unsigned short Pw[4][16 * 72];     // per-wave P [q][kv]
  const int L = blockIdx.x;
  const int xcd = L & 7, m = L >> 3;
  const int bh = xcd * 4 + (m & 3);           // XCD c owns heads 4c..4c+3 (K+V 2MB in its L2)
  const int qi = 31 - (m >> 2);               // heavy q-tiles dispatch first
  const int qbase = qi * 64;
  const int tid = threadIdx.x, wave = tid >> 6, lane = tid & 63;
  const int g = lane >> 4, lr = lane & 15;
  const unsigned short* Qb  = qb + (size_t)bh * TT * DD;
  const unsigned short* Kb  = kb + (size_t)bh * TT * DD;
  const unsigned short* Vtb = vt + (size_t)bh * DD * TT;
  const int rowbase = qbase + wave * 16;
  const int myq = rowbase + lr;               // this lane's q-row (swapped layout)

  short8 qf[2];
  #pragma unroll
  for (int kk = 0; kk < 2; ++kk)
    qf[kk] = *(const short8*)&Qb[(size_t)myq * DD + kk * 32 + g * 8];

  f32x4 acc[4];        // acc[j][r] = O^T[d=j*16+g*4+r][q=myq]
  #pragma unroll
  for (int j = 0; j < 4; ++j) acc[j] = (f32x4){0.f, 0.f, 0.f, 0.f};
  float m_i = -1e30f, l_i = 0.f;   // scalars: lane owns one q-row

  const int srow8 = lane >> 3;
  const int ssw_base = (lane & 7) * 8;

#define STAGE_KV(BUF, TI)                                                                   \
  {                                                                                         \
    const int tt = (TI);                                                                    \
    _Pragma("unroll")                                                                       \
    for (int c = 0; c < 2; ++c) {                                                           \
      const int chunk = wave * 2 + c;                                                       \
      const int row = chunk * 8 + srow8;                                                    \
      const int sw = ssw_base ^ ((row & 7) << 3);                                           \
      __builtin_amdgcn_global_load_lds(                                                     \
        (const __attribute__((address_space(1))) void*)&Kb[(size_t)(tt * 64 + row) * DD + sw], \
        (__attribute__((address_space(3))) void*)&Kbuf[BUF][chunk * 512], 16, 0, 0);        \
      __builtin_amdgcn_global_load_lds(                                                     \
        (const __attribute__((address_space(1))) void*)&Vtb[(size_t)row * TT + tt * 64 + sw], \
        (__attribute__((address_space(3))) void*)&Vbuf[BUF][chunk * 512], 16, 0, 0);        \
    }                                                                                       \
  }

  STAGE_KV(0, 0);
  __syncthreads();

  for (int t = 0; t <= qi; ++t) {
    const int cur = t & 1;
    if (t < qi) STAGE_KV(cur ^ 1, t + 1);

    // ---- S^T = K Q^T : sv[j][r] = S[q=myq][kv=t*64+j*16+g*4+r] ----
    f32x4 sv[4];
    #pragma unroll
    for (int j = 0; j < 4; ++j) sv[j] = (f32x4){0.f, 0.f, 0.f, 0.f};
    #pragma unroll
    for (int kk = 0; kk < 2; ++kk) {
      const int swc = (kk * 32 + g * 8) ^ ((lr & 7) << 3);
      short8 kf[4];
      #pragma unroll
      for (int j = 0; j < 4; ++j)
        kf[j] = *(const short8*)&Kbuf[cur][(j * 16 + lr) * 64 + swc];
      __builtin_amdgcn_s_setprio(1);
      #pragma unroll
      for (int j = 0; j < 4; ++j)
        sv[j] = __builtin_amdgcn_mfma_f32_16x16x32_bf16(kf[j], qf[kk], sv[j], 0, 0, 0);
      __builtin_amdgcn_s_setprio(0);
    }

    if (t == qi) {  // diagonal tile mask: kv > q -> -inf
      #pragma unroll
      for (int j = 0; j < 4; ++j)
        #pragma unroll
        for (int r = 0; r < 4; ++r)
          if (t * 64 + j * 16 + g * 4 + r > myq) sv[j][r] = -1e30f;
    }

    // ---- lane-local online softmax (row fully in-register; reduce over g only) ----
    float mx = -1e30f;
    #pragma unroll
    for (int j = 0; j < 4; ++j)
      #pragma unroll
      for (int r = 0; r < 4; ++r) mx = fmaxf(mx, sv[j][r]);
    mx = fmaxf(mx, __shfl_xor(mx, 16, 64));
    mx = fmaxf(mx, __shfl_xor(mx, 32, 64));
    float mnew = fmaxf(m_i, mx);
    float scl = exp2f(m_i - mnew);
    m_i = mnew;
    float rs = 0.f;
    #pragma unroll
    for (int j = 0; j < 4; ++j)
      #pragma unroll
      for (int r = 0; r < 4; ++r) {
        float p = exp2f(sv[j][r] - mnew);
        sv[j][r] = p;
        rs += p;
      }
    rs += __shfl_xor(rs, 16, 64);
    rs += __shfl_xor(rs, 32, 64);
    l_i = l_i * scl + rs;
    #pragma unroll
    for (int j = 0; j < 4; ++j)
      #pragma unroll
      for (int r = 0; r < 4; ++r) acc[j][r] *= scl;

    // ---- P -> Pw[q=lr][kv] : 4 contiguous kv per j -> packed b64 writes ----
    #pragma unroll
    for (int j = 0; j < 4; ++j) {
      uint2 pk;
      pk.x = cvtpk(sv[j][0], sv[j][1]);
      pk.y = cvtpk(sv[j][2], sv[j][3]);
      *(uint2*)&Pw[wave][lr * 72 + j * 16 + g * 4] = pk;
    }
    // ---- O^T += V^T P^T : A=V^T rows d, B=P^T cols q ----
    #pragma unroll
    for (int kk = 0; kk < 2; ++kk) {
      short8 pf = *(const short8*)&Pw[wave][lr * 72 + kk * 32 + g * 8];
      const int swc = (kk * 32 + g * 8) ^ ((lr & 7) << 3);
      short8 vf[4];
      #pragma unroll
      for (int j = 0; j < 4; ++j)
        vf[j] = *(const short8*)&Vbuf[cur][(j * 16 + lr) * 64 + swc];
      __builtin_amdgcn_s_setprio(1);
      #pragma unroll
      for (int j = 0; j < 4; ++j)
        acc[j] = __builtin_amdgcn_mfma_f32_16x16x32_bf16(vf[j], pf, acc[j], 0, 0, 0);
      __builtin_amdgcn_s_setprio(0);
    }
    __syncthreads();
  }
#undef STAGE_KV

  // write O: lane owns q=myq, d = j*16+g*4+{0..3} contiguous -> packed 8B stores
  const int b = bh >> 4, h = bh & 15;
  const float inv = 1.0f / l_i;
  size_t rowo = ((size_t)b * TT + myq) * CC + h * DD;
  #pragma unroll
  for (int j = 0; j < 4; ++j) {
    uint2 pk;
    pk.x = cvtpk(acc[j][0] * inv, acc[j][1] * inv);
    pk.y = cvtpk(acc[j][2] * inv, acc[j][3] * inv);
    *(uint2*)&aout[rowo + j * 16 + g * 4] = pk;
  }
}

extern "C" void kernel_launch(void* const* d_in, const int* in_sizes, int n_in,
                              void* d_out, int out_size, void* d_ws, size_t ws_size,
                              hipStream_t stream) {
  const float* x    = (const float*)d_in[0];
  const float* wq   = (const float*)d_in[1];
  const float* wk   = (const float*)d_in[2];
  const float* wv   = (const float*)d_in[3];
  const float* wo   = (const float*)d_in[4];
  const float* cosb = (const float*)d_in[5];
  const float* sinb = (const float*)d_in[6];
  float* out = (float*)d_out;
  char* ws = (char*)d_ws;

  const size_t MB = 1u << 20;
  unsigned short* xb    = (unsigned short*)(ws);              //  8 MB [4096,1024]
  unsigned short* wqkvb = (unsigned short*)(ws + 8 * MB);     //  6 MB [3072,1024]
  unsigned short* wob   = (unsigned short*)(ws + 14 * MB);    //  2 MB [1024,1024]
  unsigned short* sqkv  = (unsigned short*)(ws + 16 * MB);    // 24 MB [4096,3072]
  unsigned short* qb2   = (unsigned short*)(ws + 40 * MB);    //  8 MB [B,H,T,D]
  unsigned short* kb2   = (unsigned short*)(ws + 48 * MB);    //  8 MB [B,H,T,D]
  unsigned short* vtb   = (unsigned short*)(ws + 56 * MB);    //  8 MB [B,H,D,T]
  unsigned short* aoutb = (unsigned short*)(ws + 64 * MB);    //  8 MB [4096,1024]

  cvt_f32_bf16<<<2048, 256, 0, stream>>>(x,  xb, 4194304);
  cvt_f32_bf16<<<1024, 256, 0, stream>>>(wq, wqkvb,           1048576);
  cvt_f32_bf16<<<1024, 256, 0, stream>>>(wk, wqkvb + 1048576, 1048576);
  cvt_f32_bf16<<<1024, 256, 0, stream>>>(wv, wqkvb + 2097152, 1048576);
  cvt_f32_bf16<<<1024, 256, 0, stream>>>(wo, wob,             1048576);

  gemm_bt<true><<<dim3(24, 32), 256, 0, stream>>>(xb, wqkvb, sqkv, 4096, 3072, 1024);
  rope_qk<<<8192, 256, 0, stream>>>(sqkv, cosb, sinb, qb2, kb2);
  vtrans<<<dim3(32, 32), 256, 0, stream>>>(sqkv, vtb);
  attn6<<<1024, 256, 0, stream>>>(qb2, kb2, vtb, aoutb);
  gemm_bt<false><<<dim3(8, 32), 256, 0, stream>>>(aoutb, wob, out, 4096, 1024, 1024);
}